// Round 3
// baseline (589.471 us; speedup 1.0000x reference)
//
#include <hip/hip_runtime.h>

#define B_  16
#define IC  128
#define OC  256
#define ZD  256
#define HH  64
#define WW  64
#define FAN 1152      // IC*3*3
#define NO  294912    // OC*FAN
#define HP  66        // padded H/W

typedef float    fvec4 __attribute__((ext_vector_type(4)));
typedef _Float16 f16x8 __attribute__((ext_vector_type(8)));
typedef _Float16 f16x4 __attribute__((ext_vector_type(4)));

// ---------------------------------------------------------------------------
// Kernel A: delta[b][o] = sum_z z[b][z] * head_w[o][z]  via f16 MFMA.
// M = NO rows (256/block), N = 16 batches, K = 256 in 4 chunks of 64.
// Staging: per wave-instruction 4 rows x 256 B contiguous (256 B segments).
// ---------------------------------------------------------------------------
__global__ __launch_bounds__(256) void delta_gemm_kernel(
    const float* __restrict__ z, const float* __restrict__ head_w,
    float* __restrict__ delta) {
  __shared__ _Float16 As[256 * 72];     // [row][64 k + 8 pad], stride 144 B
  __shared__ _Float16 zsh[16 * 264];    // [b][256 k + 8 pad]
  int t = threadIdx.x;
  int row0 = blockIdx.x * 256;
  int lane = t & 63, wave = t >> 6;
  int quad = lane >> 4, l16 = lane & 15;

  // stage z once: 16x256 f32 -> f16
  for (int u = t; u < 1024; u += 256) {
    int b = u >> 6, kq = u & 63;
    fvec4 v = *(const fvec4*)&z[b * 256 + kq * 4];
    f16x4 h = {(_Float16)v.x, (_Float16)v.y, (_Float16)v.z, (_Float16)v.w};
    *(f16x4*)&zsh[b * 264 + kq * 4] = h;
  }

  fvec4 acc[4];
#pragma unroll
  for (int i = 0; i < 4; ++i) acc[i] = (fvec4){0.f, 0.f, 0.f, 0.f};

  int srow_lo = t >> 4;     // rows: i*16 + (t>>4), col seg: (t&15)*4 floats
  int sseg = t & 15;

  for (int zc2 = 0; zc2 < 4; ++zc2) {   // K-chunk of 64 floats
    __syncthreads();        // guards zsh on first iter, As reuse on later iters
#pragma unroll
    for (int i = 0; i < 16; ++i) {
      int row = i * 16 + srow_lo;
      fvec4 v = *(const fvec4*)&head_w[(size_t)(row0 + row) * 256 + zc2 * 64 + sseg * 4];
      f16x4 h = {(_Float16)v.x, (_Float16)v.y, (_Float16)v.z, (_Float16)v.w};
      *(f16x4*)&As[row * 72 + sseg * 4] = h;
    }
    __syncthreads();
#pragma unroll
    for (int kc = 0; kc < 2; ++kc) {
      f16x8 bfz = *(const f16x8*)&zsh[l16 * 264 + zc2 * 64 + kc * 32 + quad * 8];
#pragma unroll
      for (int mt = 0; mt < 4; ++mt) {
        f16x8 af = *(const f16x8*)&As[(wave * 64 + mt * 16 + l16) * 72 + kc * 32 + quad * 8];
        acc[mt] = __builtin_amdgcn_mfma_f32_16x16x32_f16(af, bfz, acc[mt], 0, 0, 0);
      }
    }
  }
  // D: m-row = quad*4 + r, n-col = l16 = b
#pragma unroll
  for (int mt = 0; mt < 4; ++mt) {
    int gr = row0 + wave * 64 + mt * 16 + quad * 4;
#pragma unroll
    for (int r = 0; r < 4; ++r)
      delta[(size_t)l16 * NO + gr + r] = acc[mt][r];
  }
}

// ---------------------------------------------------------------------------
// Kernel B: standardize delta over fan_in per (b,oc), add base weight,
// write f16 weights w_h[b][oc][(ky*3+kx)*128 + ic].  (round-1 validated)
// ---------------------------------------------------------------------------
__global__ __launch_bounds__(256) void standardize_kernel(
    const float* __restrict__ delta, const float* __restrict__ base_w,
    _Float16* __restrict__ w_h) {
  int b  = blockIdx.x >> 8;
  int oc = blockIdx.x & 255;
  int tid = threadIdx.x;
  const float* d = delta + (size_t)b * NO + oc * FAN;

  float s = 0.f, s2 = 0.f;
  for (int j = tid; j < FAN; j += 256) { float v = d[j]; s += v; s2 += v * v; }
#pragma unroll
  for (int off = 32; off > 0; off >>= 1) {
    s  += __shfl_down(s, off);
    s2 += __shfl_down(s2, off);
  }
  __shared__ float rs[4], rq[4];
  if ((tid & 63) == 0) { rs[tid >> 6] = s; rq[tid >> 6] = s2; }
  __syncthreads();
  float S  = rs[0] + rs[1] + rs[2] + rs[3];
  float S2 = rq[0] + rq[1] + rq[2] + rq[3];
  const float inv_fan = 1.0f / (float)FAN;
  float mu  = S * inv_fan;
  float var = S2 * inv_fan - mu * mu;
  const float inv_sqrt2 = 0.70710678118654752f;
  float sc = rsqrtf(var + 1e-5f) * sqrtf(2.0f / (float)FAN) * inv_sqrt2;

  const float* bw = base_w + oc * FAN;
  _Float16* wp = w_h + ((size_t)b * OC + oc) * FAN;
  for (int i = tid; i < FAN; i += 256) {      // i = kk*128 + ic (write order)
    int ic = i & 127, kk = i >> 7;
    int j = ic * 9 + kk;                      // read order
    float val = bw[j] * inv_sqrt2 + (d[j] - mu) * sc;
    wp[i] = (_Float16)val;
  }
}

// ---------------------------------------------------------------------------
// Kernel X: x (f32 NCHW) -> x_h (f16 NHWC, zero-padded [16][66][66][128]).
// LDS tile transpose; grid = (66 padded rows, 16 batches).
// ---------------------------------------------------------------------------
__global__ __launch_bounds__(256) void xpose_kernel(
    const float* __restrict__ x, _Float16* __restrict__ x_h) {
  int yp = blockIdx.x;
  int b  = blockIdx.y;
  int t  = threadIdx.x;
  _Float16* orow = x_h + ((size_t)(b * HP + yp)) * HP * IC;

  if (yp == 0 || yp == HP - 1) {            // full zero row (incl. corners)
    fvec4 zz = (fvec4){0.f, 0.f, 0.f, 0.f};
    for (int u = t; u < HP * IC / 8; u += 256)   // 1056 x 16B
      ((fvec4*)orow)[u] = zz;
    return;
  }
  int y = yp - 1;
  __shared__ float tile[128 * 65];          // [ic][x], stride 65 (odd: 2-way free)
#pragma unroll
  for (int i = 0; i < 8; ++i) {
    int F = i * 256 + t;
    int ic = F >> 4, xq = F & 15;
    fvec4 v = *(const fvec4*)&x[(((size_t)b * IC + ic) * HH + y) * WW + xq * 4];
    float* tp = &tile[ic * 65 + xq * 4];
    tp[0] = v.x; tp[1] = v.y; tp[2] = v.z; tp[3] = v.w;
  }
  __syncthreads();
#pragma unroll
  for (int j = 0; j < 4; ++j) {
    int u = j * 256 + t;
    int px = u >> 4, icg = u & 15;
    _Float16 h[8];
#pragma unroll
    for (int c = 0; c < 8; ++c) h[c] = (_Float16)tile[(icg * 8 + c) * 65 + px];
    *(f16x8*)&orow[(px + 1) * IC + icg * 8] = *(f16x8*)h;
  }
  if (t < 32) {                             // x' = 0 and x' = 65 pads
    int side = t >> 4, icg = t & 15;
    fvec4 zz = (fvec4){0.f, 0.f, 0.f, 0.f};
    *(fvec4*)&orow[(side ? (HP - 1) * IC : 0) + icg * 8] = zz;
  }
}

// ---------------------------------------------------------------------------
// Kernel C: conv as implicit GEMM, f16 MFMA 16x16x32 — LDS-FREE.
// Both operands are fragment-addressable in global memory:
//   w_h[b][oc][k]   row-major  -> A frags: lane(l16)=row, quad=16B k-seg
//   x_h padded NHWC            -> B frags: lane(l16)=px,  quad=16B ic-seg
// Reuse served by L1/L2 (w_h slab 288 KB/block, 32x reuse). No barriers.
// Block: 128 oc x 128 px; grid = (32 px-tiles, 2 oc-tiles, 16 b).
// ---------------------------------------------------------------------------
__global__ __launch_bounds__(256) void conv_mfma_kernel(
    const _Float16* __restrict__ x_h, const _Float16* __restrict__ w_h,
    float* __restrict__ out) {
  int t = threadIdx.x;
  int b = blockIdx.z;
  int oc0 = blockIdx.y * 128;
  int y0 = blockIdx.x * 2;
  int lane = t & 63, wave = t >> 6;
  int wm = wave >> 1, wn = wave & 1;
  int quad = lane >> 4, l16 = lane & 15;

  fvec4 acc[4][4];
#pragma unroll
  for (int i = 0; i < 4; ++i)
#pragma unroll
    for (int j = 0; j < 4; ++j) acc[i][j] = (fvec4){0.f, 0.f, 0.f, 0.f};

  // per-lane fragment base pointers
  const _Float16* ap = w_h + ((size_t)(b * OC + oc0 + wm * 64 + l16)) * FAN + quad * 8;
  const _Float16* bp = x_h + (((size_t)(b * HP + y0 + wn)) * HP + l16) * IC + quad * 8;

#pragma unroll
  for (int ky = 0; ky < 3; ++ky) {
#pragma unroll
    for (int kx = 0; kx < 3; ++kx) {
      int kk = ky * 3 + kx;
      const _Float16* apk = ap + kk * 128;
      const _Float16* bpk = bp + (ky * HP + kx) * IC;
#pragma unroll
      for (int icc = 0; icc < 2; ++icc) {
#pragma unroll
        for (int ks = 0; ks < 2; ++ks) {
          f16x8 af[4], bf[4];
#pragma unroll
          for (int i = 0; i < 4; ++i)
            af[i] = *(const f16x8*)(apk + i * (16 * FAN) + icc * 64 + ks * 32);
#pragma unroll
          for (int j = 0; j < 4; ++j)
            bf[j] = *(const f16x8*)(bpk + j * (16 * IC) + icc * 64 + ks * 32);
#pragma unroll
          for (int i = 0; i < 4; ++i)
#pragma unroll
            for (int j = 0; j < 4; ++j)
              acc[i][j] = __builtin_amdgcn_mfma_f32_16x16x32_f16(af[i], bf[j], acc[i][j], 0, 0, 0);
        }
      }
    }
  }

  // epilogue (validated): D row = oc (quad*4 + r), col = pixel (l16)
#pragma unroll
  for (int i = 0; i < 4; ++i)
#pragma unroll
    for (int j = 0; j < 4; ++j) {
      int m  = oc0 + wm * 64 + i * 16 + quad * 4;
      int nn = wn * 64 + j * 16 + l16;
      int oy = y0 + (nn >> 6), ox = nn & 63;
      float* op = out + (((size_t)(b * OC + m) * HH + oy) * WW + ox);
#pragma unroll
      for (int r = 0; r < 4; ++r)
        op[(size_t)r * HH * WW] = acc[i][j][r];
    }
}

// ---------------------------------------------------------------------------
extern "C" void kernel_launch(void* const* d_in, const int* in_sizes, int n_in,
                              void* d_out, int out_size, void* d_ws, size_t ws_size,
                              hipStream_t stream) {
  const float* x      = (const float*)d_in[0];  // [16,128,64,64]
  const float* z      = (const float*)d_in[1];  // [16,256]
  const float* base_w = (const float*)d_in[2];  // [256,128,3,3]
  const float* head_w = (const float*)d_in[3];  // [294912,256]
  float* out = (float*)d_out;                   // [16,256,64,64]

  // ws layout (peak 28.3 MB):
  //   [0, 9.44 MB)            w_h  (f16, live to the end)
  //   [9.44 MB, 28.31 MB)     delta (f32) -> REUSED as x_h (f16) after std
  _Float16* w_h   = (_Float16*)d_ws;
  float*    delta = (float*)((char*)d_ws + (size_t)B_ * OC * FAN * sizeof(_Float16));
  _Float16* x_h   = (_Float16*)delta;           // aliased: written after std reads delta

  delta_gemm_kernel<<<NO / 256, 256, 0, stream>>>(z, head_w, delta);
  standardize_kernel<<<B_ * OC, 256, 0, stream>>>(delta, base_w, w_h);
  xpose_kernel<<<dim3(HP, B_), 256, 0, stream>>>(x, x_h);   // overwrites delta region
  conv_mfma_kernel<<<dim3(32, 2, B_), 256, 0, stream>>>(x_h, w_h, out);
}

// Round 4
// 510.229 us; speedup vs baseline: 1.1553x; 1.1553x over previous
//
#include <hip/hip_runtime.h>

#define B_  16
#define IC  128
#define OC  256
#define ZD  256
#define HH  64
#define WW  64
#define FAN 1152      // IC*3*3
#define NO  294912    // OC*FAN
#define HP  66        // padded H/W

typedef float    fvec4 __attribute__((ext_vector_type(4)));
typedef _Float16 f16x8 __attribute__((ext_vector_type(8)));
typedef _Float16 f16x4 __attribute__((ext_vector_type(4)));

// async global->LDS, 16B/lane: lane i of the wave deposits at ldst + i*16B.
// Constant offsets in `g` get folded into the instruction offset field by ISel.
__device__ __forceinline__ void gl_lds16(const _Float16* g, _Float16* ldst) {
  __builtin_amdgcn_global_load_lds(
      (const __attribute__((address_space(1))) unsigned int*)(const void*)g,
      (__attribute__((address_space(3))) unsigned int*)(void*)ldst,
      16, 0, 0);
}

// ---------------------------------------------------------------------------
// Kernel A: delta[b][o] = sum_z z[b][z] * head_w[o][z]  via f16 MFMA.
// (round-3 version — HBM-stream-bound, close to floor)
// ---------------------------------------------------------------------------
__global__ __launch_bounds__(256) void delta_gemm_kernel(
    const float* __restrict__ z, const float* __restrict__ head_w,
    float* __restrict__ delta) {
  __shared__ _Float16 As[256 * 72];     // [row][64 k + 8 pad]
  __shared__ _Float16 zsh[16 * 264];    // [b][256 k + 8 pad]
  int t = threadIdx.x;
  int row0 = blockIdx.x * 256;
  int lane = t & 63, wave = t >> 6;
  int quad = lane >> 4, l16 = lane & 15;

  for (int u = t; u < 1024; u += 256) {
    int b = u >> 6, kq = u & 63;
    fvec4 v = *(const fvec4*)&z[b * 256 + kq * 4];
    f16x4 h = {(_Float16)v.x, (_Float16)v.y, (_Float16)v.z, (_Float16)v.w};
    *(f16x4*)&zsh[b * 264 + kq * 4] = h;
  }

  fvec4 acc[4];
#pragma unroll
  for (int i = 0; i < 4; ++i) acc[i] = (fvec4){0.f, 0.f, 0.f, 0.f};

  int srow_lo = t >> 4;
  int sseg = t & 15;

  for (int zc2 = 0; zc2 < 4; ++zc2) {
    __syncthreads();
#pragma unroll
    for (int i = 0; i < 16; ++i) {
      int row = i * 16 + srow_lo;
      fvec4 v = *(const fvec4*)&head_w[(size_t)(row0 + row) * 256 + zc2 * 64 + sseg * 4];
      f16x4 h = {(_Float16)v.x, (_Float16)v.y, (_Float16)v.z, (_Float16)v.w};
      *(f16x4*)&As[row * 72 + sseg * 4] = h;
    }
    __syncthreads();
#pragma unroll
    for (int kc = 0; kc < 2; ++kc) {
      f16x8 bfz = *(const f16x8*)&zsh[l16 * 264 + zc2 * 64 + kc * 32 + quad * 8];
#pragma unroll
      for (int mt = 0; mt < 4; ++mt) {
        f16x8 af = *(const f16x8*)&As[(wave * 64 + mt * 16 + l16) * 72 + kc * 32 + quad * 8];
        acc[mt] = __builtin_amdgcn_mfma_f32_16x16x32_f16(af, bfz, acc[mt], 0, 0, 0);
      }
    }
  }
#pragma unroll
  for (int mt = 0; mt < 4; ++mt) {
    int gr = row0 + wave * 64 + mt * 16 + quad * 4;
#pragma unroll
    for (int r = 0; r < 4; ++r)
      delta[(size_t)l16 * NO + gr + r] = acc[mt][r];
  }
}

// ---------------------------------------------------------------------------
// Kernel B: standardize delta, add base weight, emit f16 permuted weights.
// ---------------------------------------------------------------------------
__global__ __launch_bounds__(256) void standardize_kernel(
    const float* __restrict__ delta, const float* __restrict__ base_w,
    _Float16* __restrict__ w_h) {
  int b  = blockIdx.x >> 8;
  int oc = blockIdx.x & 255;
  int tid = threadIdx.x;
  const float* d = delta + (size_t)b * NO + oc * FAN;

  float s = 0.f, s2 = 0.f;
  for (int j = tid; j < FAN; j += 256) { float v = d[j]; s += v; s2 += v * v; }
#pragma unroll
  for (int off = 32; off > 0; off >>= 1) {
    s  += __shfl_down(s, off);
    s2 += __shfl_down(s2, off);
  }
  __shared__ float rs[4], rq[4];
  if ((tid & 63) == 0) { rs[tid >> 6] = s; rq[tid >> 6] = s2; }
  __syncthreads();
  float S  = rs[0] + rs[1] + rs[2] + rs[3];
  float S2 = rq[0] + rq[1] + rq[2] + rq[3];
  const float inv_fan = 1.0f / (float)FAN;
  float mu  = S * inv_fan;
  float var = S2 * inv_fan - mu * mu;
  const float inv_sqrt2 = 0.70710678118654752f;
  float sc = rsqrtf(var + 1e-5f) * sqrtf(2.0f / (float)FAN) * inv_sqrt2;

  const float* bw = base_w + oc * FAN;
  _Float16* wp = w_h + ((size_t)b * OC + oc) * FAN;
  for (int i = tid; i < FAN; i += 256) {
    int ic = i & 127, kk = i >> 7;
    int j = ic * 9 + kk;
    float val = bw[j] * inv_sqrt2 + (d[j] - mu) * sc;
    wp[i] = (_Float16)val;
  }
}

// ---------------------------------------------------------------------------
// Kernel X: x (f32 NCHW) -> x_h (f16 NHWC, zero-padded [16][66][66][128]).
// ---------------------------------------------------------------------------
__global__ __launch_bounds__(256) void xpose_kernel(
    const float* __restrict__ x, _Float16* __restrict__ x_h) {
  int yp = blockIdx.x;
  int b  = blockIdx.y;
  int t  = threadIdx.x;
  _Float16* orow = x_h + ((size_t)(b * HP + yp)) * HP * IC;

  if (yp == 0 || yp == HP - 1) {
    fvec4 zz = (fvec4){0.f, 0.f, 0.f, 0.f};
    for (int u = t; u < HP * IC / 8; u += 256)
      ((fvec4*)orow)[u] = zz;
    return;
  }
  int y = yp - 1;
  __shared__ float tile[128 * 65];
#pragma unroll
  for (int i = 0; i < 8; ++i) {
    int F = i * 256 + t;
    int ic = F >> 4, xq = F & 15;
    fvec4 v = *(const fvec4*)&x[(((size_t)b * IC + ic) * HH + y) * WW + xq * 4];
    float* tp = &tile[ic * 65 + xq * 4];
    tp[0] = v.x; tp[1] = v.y; tp[2] = v.z; tp[3] = v.w;
  }
  __syncthreads();
#pragma unroll
  for (int j = 0; j < 4; ++j) {
    int u = j * 256 + t;
    int px = u >> 4, icg = u & 15;
    _Float16 h[8];
#pragma unroll
    for (int c = 0; c < 8; ++c) h[c] = (_Float16)tile[(icg * 8 + c) * 65 + px];
    *(f16x8*)&orow[(px + 1) * IC + icg * 8] = *(f16x8*)h;
  }
  if (t < 32) {
    int side = t >> 4, icg = t & 15;
    fvec4 zz = (fvec4){0.f, 0.f, 0.f, 0.f};
    *(fvec4*)&orow[(side ? (HP - 1) * IC : 0) + icg * 8] = zz;
  }
}

// ---------------------------------------------------------------------------
// Kernel C: implicit-GEMM conv, f16 MFMA 16x16x32, BK=64.
// LDS staging via global_load_lds width=16 (async DMA, no VGPR round-trip).
// Unpadded 128x64 tiles + XOR swizzle (slot = seg ^ (row&7)):
//   - DMA dest is lane-linear (required), source lanes permuted per row
//   - fragment b128 reads hit 32 banks at 2 lanes/bank (free, m136)
// Block: 128 oc x 128 px; grid = (32 px-tiles, 2 oc-tiles, 16 b).
// ---------------------------------------------------------------------------
__global__ __launch_bounds__(256) void conv_mfma_kernel(
    const _Float16* __restrict__ x_h, const _Float16* __restrict__ w_h,
    float* __restrict__ out) {
  __shared__ __align__(16) _Float16 As[128 * 64];   // 16 KB, slot-swizzled
  __shared__ __align__(16) _Float16 Bs[128 * 64];   // 16 KB, slot-swizzled
  int t = threadIdx.x;
  int b = blockIdx.z;
  int oc0 = blockIdx.y * 128;
  int y0 = blockIdx.x * 2;
  int lane = t & 63, wave = t >> 6;
  int wm = wave >> 1, wn = wave & 1;
  int quad = lane >> 4, l16 = lane & 15;

  fvec4 acc[4][4];
#pragma unroll
  for (int i = 0; i < 4; ++i)
#pragma unroll
    for (int j = 0; j < 4; ++j) acc[i][j] = (fvec4){0.f, 0.f, 0.f, 0.f};

  // ---- staging source mapping (per wave: rows wave*32 .. +31, 8 rows/instr)
  int lrow = lane >> 3;              // row within 8-row group; row&7 == lrow
  int lseg = lane & 7;               // dest 16B slot
  int sw   = lseg ^ lrow;            // swizzled source segment

  // A: 4 per-lane global pointers (n = 0..3)
  const _Float16* apg[4];
#pragma unroll
  for (int n = 0; n < 4; ++n)
    apg[n] = w_h + ((size_t)(b * OC + oc0 + wave * 32 + n * 8 + lrow)) * FAN + sw * 8;

  // B: px = wave*32 + n*8 + lrow -> ry = wave>>1, xoff = (wave&1)*32 + n*8 + lrow
  const _Float16* bpg0 =
      x_h + (((size_t)(b * HP + y0 + (wave >> 1))) * HP + (wave & 1) * 32 + lrow) * IC + sw * 8;
  const _Float16* bpg1 = bpg0 + 16 * IC;   // n = 2,3

  // LDS DMA dest bases (wave-uniform)
  _Float16* adst = As + wave * 32 * 64;
  _Float16* bdst = Bs + wave * 32 * 64;

  // ---- fragment read offsets (elements); row&7 == l16&7 for frag rows
  int s7 = l16 & 7;
  int arow = (wm * 64 + l16) * 64;
  int brow = (wn * 64 + l16) * 64;
  int aoff[2] = { arow + ((0 + quad) ^ s7) * 8, arow + ((4 + quad) ^ s7) * 8 };
  int boff[2] = { brow + ((0 + quad) ^ s7) * 8, brow + ((4 + quad) ^ s7) * 8 };

#pragma unroll
  for (int ky = 0; ky < 3; ++ky) {
#pragma unroll
    for (int kx = 0; kx < 3; ++kx) {
      const int kk = ky * 3 + kx;
      const _Float16* b0k = bpg0 + (ky * HP + kx) * IC;
      const _Float16* b1k = bpg1 + (ky * HP + kx) * IC;
#pragma unroll
      for (int icc = 0; icc < 2; ++icc) {
        __syncthreads();              // previous iteration's readers done
#pragma unroll
        for (int n = 0; n < 4; ++n)
          gl_lds16(apg[n] + kk * 128 + icc * 64, adst + n * 512);
        gl_lds16(b0k + icc * 64,        bdst);
        gl_lds16(b0k + 1024 + icc * 64, bdst + 512);
        gl_lds16(b1k + icc * 64,        bdst + 1024);
        gl_lds16(b1k + 1024 + icc * 64, bdst + 1536);
        __syncthreads();              // drains vmcnt: DMA data visible
#pragma unroll
        for (int ks = 0; ks < 2; ++ks) {
          f16x8 af[4], bf[4];
#pragma unroll
          for (int i = 0; i < 4; ++i)
            af[i] = *(const f16x8*)&As[aoff[ks] + i * 1024];
#pragma unroll
          for (int j = 0; j < 4; ++j)
            bf[j] = *(const f16x8*)&Bs[boff[ks] + j * 1024];
#pragma unroll
          for (int i = 0; i < 4; ++i)
#pragma unroll
            for (int j = 0; j < 4; ++j)
              acc[i][j] = __builtin_amdgcn_mfma_f32_16x16x32_f16(af[i], bf[j], acc[i][j], 0, 0, 0);
        }
      }
    }
  }

  // epilogue (validated): D row = oc (quad*4 + r), col = pixel (l16)
#pragma unroll
  for (int i = 0; i < 4; ++i)
#pragma unroll
    for (int j = 0; j < 4; ++j) {
      int m  = oc0 + wm * 64 + i * 16 + quad * 4;
      int nn = wn * 64 + j * 16 + l16;
      int oy = y0 + (nn >> 6), ox = nn & 63;
      float* op = out + (((size_t)(b * OC + m) * HH + oy) * WW + ox);
#pragma unroll
      for (int r = 0; r < 4; ++r)
        op[(size_t)r * HH * WW] = acc[i][j][r];
    }
}

// ---------------------------------------------------------------------------
extern "C" void kernel_launch(void* const* d_in, const int* in_sizes, int n_in,
                              void* d_out, int out_size, void* d_ws, size_t ws_size,
                              hipStream_t stream) {
  const float* x      = (const float*)d_in[0];  // [16,128,64,64]
  const float* z      = (const float*)d_in[1];  // [16,256]
  const float* base_w = (const float*)d_in[2];  // [256,128,3,3]
  const float* head_w = (const float*)d_in[3];  // [294912,256]
  float* out = (float*)d_out;                   // [16,256,64,64]

  // ws layout (no aliasing; ~46 MB of ~1.2 GB):
  //   [0)        w_h   f16  9.44 MB
  //   [+9.44MB)  delta f32 18.87 MB
  //   [+28.3MB)  x_h   f16 17.84 MB
  _Float16* w_h   = (_Float16*)d_ws;
  float*    delta = (float*)((char*)d_ws + (size_t)B_ * OC * FAN * sizeof(_Float16));
  _Float16* x_h   = (_Float16*)((char*)d_ws + (size_t)B_ * OC * FAN * sizeof(_Float16)
                                            + (size_t)B_ * NO * sizeof(float));

  delta_gemm_kernel<<<NO / 256, 256, 0, stream>>>(z, head_w, delta);
  standardize_kernel<<<B_ * OC, 256, 0, stream>>>(delta, base_w, w_h);
  xpose_kernel<<<dim3(HP, B_), 256, 0, stream>>>(x, x_h);
  conv_mfma_kernel<<<dim3(32, 2, B_), 256, 0, stream>>>(x_h, w_h, out);
}